// Round 15
// baseline (566.804 us; speedup 1.0000x reference)
//
#include <hip/hip_runtime.h>

// Problem constants (fixed by reference)
#define R_   3
#define N_   50000
#define E_   400000
#define IN_  128
#define HID_ 64
#define C_   40
#define H_   3
#define NEG_SLOPE 0.2f

#define SCAN_CHUNK 1024
#define NCH  49                  // ceil(N_/1024)
#define CAPE (E_ + 8 * N_)       // padded csr capacity per relation (800k)

typedef _Float16 half_t;
typedef _Float16 f16x8 __attribute__((ext_vector_type(8)));
typedef _Float16 f16x4 __attribute__((ext_vector_type(4)));
typedef float float4v __attribute__((ext_vector_type(4)));

template <int V> struct vecT;
template <> struct vecT<4> { typedef f16x4 type; };
template <> struct vecT<8> { typedef f16x8 type; };

// ---------------- fused prep: cast feat, transpose W1/W2, zero deg, sentinels ----
__global__ __launch_bounds__(256) void prep_kernel(
        const float* __restrict__ feat, const float* __restrict__ W1,
        const float* __restrict__ W2, half_t* __restrict__ featH,
        half_t* __restrict__ W1t, half_t* __restrict__ W2t,
        int* __restrict__ deg, float* __restrict__ el, half_t* __restrict__ zbuf) {
    const int nCast = N_ * IN_ / 4;
    const int nW1 = R_ * IN_ * (H_ * HID_);
    const int nW2 = R_ * HID_ * (H_ * C_);
    const int nDeg = R_ * N_;
    const int nSent = R_ * H_;
    const int nZs = R_ * 48;       // sentinel z row: 192 halves = 48 f16x4 per rel
    int idx = blockIdx.x * 256 + threadIdx.x;
    if (idx < nCast) {
        float4 v = ((const float4*)feat)[idx];
        f16x4 h;
        h[0] = (half_t)v.x; h[1] = (half_t)v.y;
        h[2] = (half_t)v.z; h[3] = (half_t)v.w;
        ((f16x4*)featH)[idx] = h;
        return;
    }
    idx -= nCast;
    if (idx < nW1) {
        const int K = IN_, Nc = H_ * HID_;
        int r = idx / (K * Nc), rem = idx - r * K * Nc;
        int n = rem / K, k = rem - n * K;
        W1t[idx] = (half_t)W1[((size_t)r * K + k) * Nc + n];
        return;
    }
    idx -= nW1;
    if (idx < nW2) {
        const int K = HID_, Nc = H_ * C_;
        int r = idx / (K * Nc), rem = idx - r * K * Nc;
        int n = rem / K, k = rem - n * K;
        W2t[idx] = (half_t)W2[((size_t)r * K + k) * Nc + n];
        return;
    }
    idx -= nW2;
    if (idx < nDeg) { deg[idx] = 0; return; }
    idx -= nDeg;
    if (idx < nSent) {
        int r = idx / H_, h = idx - r * H_;
        el[(size_t)r * (N_ + 1) * H_ + (size_t)N_ * H_ + h] = -1.0e30f;
        return;
    }
    idx -= nSent;
    if (idx < nZs) {
        int r = idx / 48, k = idx - r * 48;
        f16x4 zv = {};
        ((f16x4*)(zbuf + (size_t)r * (N_ + 1) * 192 + (size_t)N_ * 192))[k] = zv;
    }
}

// ---------------- CSR build ----------------
__global__ void hist_kernel(const int* __restrict__ dst, int* __restrict__ deg) {
    int idx = blockIdx.x * 256 + threadIdx.x;
    if (idx < R_ * E_) {
        int r = idx / E_;
        atomicAdd(&deg[r * N_ + dst[idx]], 1);
    }
}

// fused scan: padded uniform geometry. Block ch: (1) redundant prefix of slots
// over nodes < ch*1024 (deg is L2-resident), (2) block scan of own chunk,
// writes rowptrP + per-relation cursors, (3) sentinel-prefills csr span.
__global__ __launch_bounds__(256) void scan2_kernel(
        const int* __restrict__ deg, int* __restrict__ rowptrP,
        int* __restrict__ cursor, int* __restrict__ csr) {
    int ch = blockIdx.x, tid = threadIdx.x;
    int base = ch * SCAN_CHUNK;
    // (1) prefix over earlier nodes
    int pre = 0;
    for (int j = tid; j < base; j += 256) {
        int m = max(deg[j], max(deg[N_ + j], deg[2 * N_ + j]));
        pre += (m + 3) & ~3;
    }
    __shared__ int red[256];
    red[tid] = pre; __syncthreads();
    for (int off = 128; off; off >>= 1) {
        if (tid < off) red[tid] += red[tid + off];
        __syncthreads();
    }
    int blockStart = red[0];
    __syncthreads();
    // (2) own chunk: 4 nodes per thread
    int v[4]; int s = 0;
    int nb = base + tid * 4;
    for (int j = 0; j < 4; ++j) {
        int n = nb + j; int sl = 0;
        if (n < N_) {
            int m = max(deg[n], max(deg[N_ + n], deg[2 * N_ + n]));
            sl = (m + 3) & ~3;
        }
        v[j] = sl; s += sl;
    }
    __shared__ int buf[256];
    buf[tid] = s; __syncthreads();
    for (int off = 1; off < 256; off <<= 1) {
        int t2 = (tid >= off) ? buf[tid - off] : 0;
        __syncthreads();
        buf[tid] += t2;
        __syncthreads();
    }
    int run = buf[tid] - s + blockStart;
    for (int j = 0; j < 4; ++j) {
        int n = nb + j;
        if (n < N_) {
            rowptrP[n] = run;
            #pragma unroll
            for (int r = 0; r < R_; ++r) cursor[r * N_ + n] = run;
            run += v[j];
            if (n == N_ - 1) rowptrP[N_] = run;
        }
    }
    // (3) sentinel prefill of this chunk's span (contiguous, coalesced)
    int chunkTotal = buf[255];
    for (int r = 0; r < R_; ++r)
        for (int p = blockStart + tid; p < blockStart + chunkTotal; p += 256)
            csr[(size_t)r * CAPE + p] = N_;
}

__global__ void fill_kernel(const int* __restrict__ src, const int* __restrict__ dst,
                            int* __restrict__ cursor, int* __restrict__ csr) {
    int idx = blockIdx.x * 256 + threadIdx.x;
    if (idx < R_ * E_) {
        int r = idx / E_;
        int pos = atomicAdd(&cursor[r * N_ + dst[idx]], 1);
        csr[(size_t)r * CAPE + pos] = src[idx];
    }
}

// ---------------- MFMA GEMM: Z[r] = A @ Bt[r]^T (relation stride (N+1)*Nc) ------
template <int K>
__global__ __launch_bounds__(256) void mfma_gemm_kernel(
        const half_t* __restrict__ A, const half_t* __restrict__ Bt,
        half_t* __restrict__ Z, int M, int Nc) {
    int r = blockIdx.z;
    int wave = threadIdx.x >> 6, lane = threadIdx.x & 63;
    int lrow = lane & 15, lq = lane >> 4;
    int rowA = blockIdx.x * 64 + wave * 16 + lrow;
    int col0 = blockIdx.y * 64;
    const half_t* Btr = Bt + (size_t)r * Nc * K;
    const half_t* aP = A + (size_t)rowA * K + lq * 8;
    bool arow_ok = (rowA < M);
    f16x8 zv8 = {};
    float4v acc[4] = {};
    #pragma unroll
    for (int k0 = 0; k0 < K; k0 += 32) {
        f16x8 af = arow_ok ? *(const f16x8*)(aP + k0) : zv8;
        #pragma unroll
        for (int ct = 0; ct < 4; ++ct) {
            int col = col0 + ct * 16 + lrow;
            f16x8 bf = (col < Nc) ? *(const f16x8*)(Btr + (size_t)col * K + lq * 8 + k0) : zv8;
            acc[ct] = __builtin_amdgcn_mfma_f32_16x16x32_f16(af, bf, acc[ct], 0, 0, 0);
        }
    }
    half_t* Zr = Z + (size_t)r * (N_ + 1) * Nc;
    int rbase = blockIdx.x * 64 + wave * 16 + lq * 4;
    #pragma unroll
    for (int ct = 0; ct < 4; ++ct) {
        int col = col0 + ct * 16 + lrow;
        if (col >= Nc) continue;
        #pragma unroll
        for (int g = 0; g < 4; ++g) {
            int row = rbase + g;
            if (row < M) Zr[(size_t)row * Nc + col] = (half_t)acc[ct][g];
        }
    }
}

// ---------------- attention logits: one THREAD per (r,n,h) ----------------
// el layout [R][(N+1)][H] (sentinel slot at n=N untouched); er [R][N][H].
template <int Dd>
__global__ __launch_bounds__(256) void attn2_kernel(
        const half_t* __restrict__ z, const float* __restrict__ al,
        const float* __restrict__ ar, float* __restrict__ el,
        float* __restrict__ er) {
    int t = blockIdx.x * 256 + threadIdx.x;
    if (t >= R_ * N_ * H_) return;
    int rn = t / H_, h = t - rn * H_;
    int r = rn / N_, n = rn - r * N_;
    const half_t* zrow = z + ((size_t)r * (N_ + 1) + n) * (3 * Dd) + h * Dd;
    const float* alp = al + (r * H_ + h) * Dd;
    const float* arp = ar + (r * H_ + h) * Dd;
    float p0 = 0.f, p1 = 0.f, q0 = 0.f, q1 = 0.f;
    #pragma unroll
    for (int c = 0; c < Dd / 8; ++c) {
        f16x8 zv = *(const f16x8*)(zrow + c * 8);
        #pragma unroll
        for (int j = 0; j < 8; j += 2) {
            float za = (float)zv[j], zb = (float)zv[j + 1];
            p0 += za * alp[c * 8 + j];
            p1 += zb * alp[c * 8 + j + 1];
            q0 += za * arp[c * 8 + j];
            q1 += zb * arp[c * 8 + j + 1];
        }
    }
    el[t + r * H_] = p0 + p1;   // [R][(N+1)][H] layout
    er[t] = q0 + q1;
}

// ---------------- fused softmax + gather + aggregate (v10: padded, no guards) ---
// One wave per node; all 3 relations share padded row geometry: single uniform
// loop t<T, NO per-edge guards, no tail (sentinel node N has el=-1e30 -> c=0;
// its z row is zeroed). fp16 packed accumulation (v_pk_fma_f16), fp32 l.
// Epilogue: cvt once, lane^32 combine (l replicated per head group), bias/relu,
// cyclic head-sum, redistribute, plain coalesced store.
template <int Dd, int VEC, bool RELU, typename OutT>
__global__ __launch_bounds__(256) void agg13_kernel(
        const int* __restrict__ rowptrP, const int* __restrict__ csr,
        const half_t* __restrict__ z, const float* __restrict__ el,
        const float* __restrict__ er, const float* __restrict__ bias,
        OutT* __restrict__ out, float scale) {
    constexpr int ROWH = 3 * Dd;
    constexpr int LPE  = ROWH / VEC;    // 30 / 24
    constexpr int PH   = Dd / VEC;      // 10 / 8
    using fv = typename vecT<VEC>::type;
    int n = blockIdx.x * 4 + (threadIdx.x >> 6);
    int lane = threadIdx.x & 63;
    if (n >= N_) return;
    int hf = lane >> 5;
    int sub = lane & 31;
    bool act = sub < LPE;
    int hl = act ? sub / PH : 0;
    int dl = act ? sub - hl * PH : 0;
    int zoff = VEC * sub;
    int b0 = rowptrP[n];
    int T = (rowptrP[n + 1] - b0) >> 2;
    const int* csP[R_];
    const half_t* zr[R_];
    const float* elr[R_];
    float ervv[R_];
    #pragma unroll
    for (int r = 0; r < R_; ++r) {
        csP[r] = csr + (size_t)r * CAPE + b0;
        zr[r] = z + (size_t)r * (N_ + 1) * ROWH;
        elr[r] = el + (size_t)r * (N_ + 1) * H_;
        ervv[r] = er[((size_t)r * N_ + n) * H_ + hl];
    }
    fv ah[R_] = {};
    float ll[R_] = {};
    for (int t = 0; t < T; ++t) {
        int i4 = 4 * t;
        int sA[R_], sB[R_];
        float xA[R_], xB[R_];
        fv zA[R_], zB[R_];
        #pragma unroll
        for (int r = 0; r < R_; ++r) {
            sA[r] = csP[r][i4 + hf];
            sB[r] = csP[r][i4 + 2 + hf];
            xA[r] = elr[r][sA[r] * H_ + hl] + ervv[r];
            xB[r] = elr[r][sB[r] * H_ + hl] + ervv[r];
            zA[r] = {}; zB[r] = {};
            if (act) {
                zA[r] = *(const fv*)(zr[r] + sA[r] * ROWH + zoff);
                zB[r] = *(const fv*)(zr[r] + sB[r] * ROWH + zoff);
            }
        }
        #pragma unroll
        for (int r = 0; r < R_; ++r) {
            float xa = xA[r]; xa = fmaxf(xa, NEG_SLOPE * xa);
            float xb = xB[r]; xb = fmaxf(xb, NEG_SLOPE * xb);
            float cA = __expf(xa), cB = __expf(xb);   // sentinel -> 0
            ll[r] += cA + cB;
            half_t hA = (half_t)cA, hB = (half_t)cB;
            fv vA, vB;
            #pragma unroll
            for (int v = 0; v < VEC; ++v) { vA[v] = hA; vB[v] = hB; }
            ah[r] += vA * zA[r] + vB * zB[r];   // v_pk_fma_f16
        }
    }
    // ---- epilogue ----
    float aa[R_][VEC];
    #pragma unroll
    for (int r = 0; r < R_; ++r)
        #pragma unroll
        for (int v = 0; v < VEC; ++v) aa[r][v] = (float)ah[r][v];
    #pragma unroll
    for (int r = 0; r < R_; ++r) {
        #pragma unroll
        for (int v = 0; v < VEC; ++v) aa[r][v] += __shfl(aa[r][v], lane ^ 32);
        ll[r] += __shfl(ll[r], lane ^ 32);
    }
    float vacc[VEC] = {};
    #pragma unroll
    for (int r = 0; r < R_; ++r) {
        float li = (ll[r] > 0.f) ? 1.f / ll[r] : 0.f;
        const float* br = bias + r * ROWH + hl * Dd + VEC * dl;
        #pragma unroll
        for (int v = 0; v < VEC; ++v) {
            float t = aa[r][v] * li + br[v];
            if (RELU) t = fmaxf(t, 0.f);
            vacc[v] += t;
        }
    }
    int base = lane & 32;
    int p1 = sub + PH;     if (p1 >= LPE) p1 -= LPE;
    int p2 = sub + 2 * PH; if (p2 >= LPE) p2 -= LPE;
    #pragma unroll
    for (int v = 0; v < VEC; ++v)
        vacc[v] += __shfl(vacc[v], base + p1) + __shfl(vacc[v], base + p2);
    int srcl = lane / VEC;
    int cm = lane & (VEC - 1);
    float tv[VEC];
    #pragma unroll
    for (int v = 0; v < VEC; ++v) tv[v] = __shfl(vacc[v], srcl);
    float outv = tv[0];
    #pragma unroll
    for (int v = 1; v < VEC; ++v) outv = (cm == v) ? tv[v] : outv;
    if (lane < Dd) out[(size_t)n * Dd + lane] = (OutT)(outv * scale);
}

// ---------------- launch ----------------
static inline size_t align256(size_t x) { return (x + 255) & ~(size_t)255; }

extern "C" void kernel_launch(void* const* d_in, const int* in_sizes, int n_in,
                              void* d_out, int out_size, void* d_ws, size_t ws_size,
                              hipStream_t stream) {
    const float* feat = (const float*)d_in[0];
    const int*   src  = (const int*)d_in[1];
    const int*   dst  = (const int*)d_in[2];
    const float* W1   = (const float*)d_in[3];
    const float* al1  = (const float*)d_in[4];
    const float* ar1  = (const float*)d_in[5];
    const float* b1   = (const float*)d_in[6];
    const float* W2   = (const float*)d_in[7];
    const float* al2  = (const float*)d_in[8];
    const float* ar2  = (const float*)d_in[9];
    const float* b2   = (const float*)d_in[10];
    float* out = (float*)d_out;

    // workspace carve
    char* ws = (char*)d_ws;
    size_t off = 0;
    half_t* zbuf = (half_t*)(ws + off); off += align256((size_t)R_ * (N_ + 1) * (3 * HID_) * 2);
    half_t* featH = (half_t*)(ws + off); off += align256((size_t)N_ * IN_ * 2);
    half_t* h1h  = (half_t*)(ws + off); off += align256((size_t)N_ * HID_ * 2);
    half_t* W1t  = (half_t*)(ws + off); off += align256((size_t)R_ * (H_ * HID_) * IN_ * 2);
    half_t* W2t  = (half_t*)(ws + off); off += align256((size_t)R_ * (H_ * C_) * HID_ * 2);
    float* el   = (float*)(ws + off); off += align256((size_t)R_ * (N_ + 1) * H_ * 4);
    float* er   = (float*)(ws + off); off += align256((size_t)R_ * N_ * H_ * 4);
    int* deg    = (int*)(ws + off);   off += align256((size_t)R_ * N_ * 4);
    int* rowptrP = (int*)(ws + off);  off += align256((size_t)(N_ + 1) * 4);
    int* cursor = (int*)(ws + off);   off += align256((size_t)R_ * N_ * 4);
    int* csr    = (int*)(ws + off);   off += align256((size_t)R_ * CAPE * 4);
    (void)ws_size; (void)n_in; (void)in_sizes; (void)out_size;

    const int EDGE_BLOCKS = (R_ * E_ + 255) / 256;     // 4688
    const int ROW_TILES = (N_ + 63) / 64;              // 782
    const int NODE_WAVES = (N_ + 3) / 4;               // 12500
    const int ATTN_BLOCKS = (R_ * N_ * H_ + 255) / 256;// 1758
    const int PREP_ITEMS = N_ * IN_ / 4 + R_ * IN_ * (H_ * HID_)
                         + R_ * HID_ * (H_ * C_) + R_ * N_ + R_ * H_ + R_ * 48;
    const int PREP_BLOCKS = (PREP_ITEMS + 255) / 256;

    // ---- prep (cast, transpose, zero deg, sentinels) ----
    prep_kernel<<<PREP_BLOCKS, 256, 0, stream>>>(feat, W1, W2, featH, W1t, W2t,
                                                 deg, el, zbuf);
    // ---- CSR build (padded uniform geometry, shared by both layers) ----
    hist_kernel<<<EDGE_BLOCKS, 256, 0, stream>>>(dst, deg);
    scan2_kernel<<<NCH, 256, 0, stream>>>(deg, rowptrP, cursor, csr);
    fill_kernel<<<EDGE_BLOCKS, 256, 0, stream>>>(src, dst, cursor, csr);

    // ---- layer 1: IN -> H*HID, relu; agg writes h1h (fp16) directly ----
    mfma_gemm_kernel<IN_><<<dim3(ROW_TILES, 3, R_), 256, 0, stream>>>(
        featH, W1t, zbuf, N_, H_ * HID_);
    attn2_kernel<HID_><<<ATTN_BLOCKS, 256, 0, stream>>>(zbuf, al1, ar1, el, er);
    agg13_kernel<HID_, 8, true, half_t><<<NODE_WAVES, 256, 0, stream>>>(
        rowptrP, csr, zbuf, el, er, b1, h1h, 1.f / (H_ * R_));

    // ---- layer 2: HID -> H*C, no relu; agg writes d_out (fp32) directly ----
    mfma_gemm_kernel<HID_><<<dim3(ROW_TILES, 2, R_), 256, 0, stream>>>(
        h1h, W2t, zbuf, N_, H_ * C_);
    attn2_kernel<C_><<<ATTN_BLOCKS, 256, 0, stream>>>(zbuf, al2, ar2, el, er);
    agg13_kernel<C_, 4, false, float><<<NODE_WAVES, 256, 0, stream>>>(
        rowptrP, csr, zbuf, el, er, b2, out, 1.f / (H_ * R_));
}